// Round 3
// baseline (168.592 us; speedup 1.0000x reference)
//
#include <hip/hip_runtime.h>

#define GAMMA 0.1f

constexpr int MTOT = 65536;
constexpr int NTOT = 1024;
constexpr int KDIM = 64;
constexpr int BM = 64;     // x rows per m-tile
constexpr int BN = 128;    // centers per block (nt = blockIdx.x & 7)
constexpr int TILES = 4;   // m-tiles per block -> grid = 8 * (65536/64/4) = 2048

using frag_ab = __attribute__((ext_vector_type(8))) short;  // 8 bf16
using f32x4   = __attribute__((ext_vector_type(4))) float;  // 4 f32 acc

// f32 -> bf16 round-to-nearest-even; 'back' is the rounded value as f32.
__device__ __forceinline__ ushort bf16_rne(float x, float& back) {
  unsigned u = __float_as_uint(x);
  unsigned r = (u + 0x7FFFu + ((u >> 16) & 1u)) >> 16;
  back = __uint_as_float(r << 16);
  return (ushort)r;
}

// Tile 64(m) x 128(n), K=64. A-role = centers (from LDS, staged once),
// B-role = x (direct-from-global f32, converted in-register). The m-loop has
// no barriers and no LDS writes, so waves free-run and stores stream.
__global__ __launch_bounds__(256, 4)
void rbf_kernel(const float* __restrict__ x,
                const float* __restrict__ centers,
                float* __restrict__ out) {
  __shared__ ushort sChi[BN * KDIM];   // 16 KB
  __shared__ ushort sClo[BN * KDIM];   // 16 KB
  __shared__ float  sCsq[BN];          // 512 B

  const int tid = threadIdx.x;
  const int nt = blockIdx.x & 7;       // one nt per XCD (round-robin dispatch)
  const int mc = blockIdx.x >> 3;      // 0..255

  // ---- stage centers tile ONCE: f32 -> bf16 hi/lo (XOR-swizzled) + csq ----
  #pragma unroll
  for (int p = 0; p < 4; ++p) {
    const int c = p * 256 + tid;       // 8-elem chunk id within the 128x64 tile
    const int row = c >> 3;
    const int s = c & 7;
    const float4* pc = reinterpret_cast<const float4*>(
        centers + ((size_t)nt * BN + row) * KDIM + s * 8);
    float4 v0 = pc[0], v1 = pc[1];
    float v[8] = {v0.x, v0.y, v0.z, v0.w, v1.x, v1.y, v1.z, v1.w};
    frag_ab hv, lv;
    float ss = 0.0f;
    #pragma unroll
    for (int i = 0; i < 8; ++i) {
      float back;
      ushort hb = bf16_rne(v[i], back);
      float b2;
      ushort lb = bf16_rne(v[i] - back, b2);
      (void)b2;
      ss += v[i] * v[i];
      hv[i] = (short)hb;
      lv[i] = (short)lb;
    }
    ss += __shfl_xor(ss, 1);
    ss += __shfl_xor(ss, 2);
    ss += __shfl_xor(ss, 4);
    if (s == 0) sCsq[row] = ss;
    const int slot = s ^ (row & 7);    // bank-conflict XOR swizzle
    *reinterpret_cast<frag_ab*>(sChi + row * KDIM + slot * 8) = hv;
    *reinterpret_cast<frag_ab*>(sClo + row * KDIM + slot * 8) = lv;
  }
  __syncthreads();   // the ONLY barrier

  const int lane = tid & 63;
  const int wave = tid >> 6;
  const int wn = wave >> 1;            // n-half (64 centers)
  const int wm = wave & 1;             // m-half (32 x-rows)
  const int r16 = lane & 15;
  const int g = lane >> 4;             // k-group 0..3

  const int n0l = wn * 64;             // LDS n base
  const int n0g = nt * 128 + wn * 64;  // global n base

  #pragma unroll 1
  for (int t = 0; t < TILES; ++t) {
    const int m0 = (mc * TILES + t) * BM;

    // ---- x fragments: direct global f32 reads in frag order + in-reg convert ----
    float ss[2] = {0.0f, 0.0f};
    frag_ab xh[2][2], xl[2][2];        // [ks][mf]
    #pragma unroll
    for (int ks = 0; ks < 2; ++ks) {
      #pragma unroll
      for (int mf = 0; mf < 2; ++mf) {
        const float* xp = x + ((size_t)m0 + wm * 32 + mf * 16 + r16) * KDIM + ks * 32 + g * 8;
        float4 a0 = *reinterpret_cast<const float4*>(xp);
        float4 a1 = *reinterpret_cast<const float4*>(xp + 4);
        float v[8] = {a0.x, a0.y, a0.z, a0.w, a1.x, a1.y, a1.z, a1.w};
        frag_ab h, l;
        #pragma unroll
        for (int i = 0; i < 8; ++i) {
          float back;
          ushort hb = bf16_rne(v[i], back);
          float lo = v[i] - back;                      // exact residual
          ushort lb = (ushort)(__float_as_uint(lo) >> 16);  // trunc: 2nd-order err
          ss[mf] += v[i] * v[i];
          h[i] = (short)hb;
          l[i] = (short)lb;
        }
        xh[ks][mf] = h;
        xl[ks][mf] = l;
      }
    }
    // reduce xsq across the 4 k-groups (lanes r16, r16+16, r16+32, r16+48)
    ss[0] += __shfl_xor(ss[0], 16); ss[0] += __shfl_xor(ss[0], 32);
    ss[1] += __shfl_xor(ss[1], 16); ss[1] += __shfl_xor(ss[1], 32);

    // ---- MFMA: cross = ch*xh + ch*xl + cl*xh (lo*lo dropped) ----
    f32x4 acc[4][2] = {};              // [nf][mf]
    #pragma unroll
    for (int ks = 0; ks < 2; ++ks) {
      const int slot = (ks * 4 + g) ^ (r16 & 7);   // row&7 == r16&7 here
      #pragma unroll
      for (int nf = 0; nf < 4; ++nf) {
        const int row = n0l + nf * 16 + r16;
        frag_ab ch = *reinterpret_cast<const frag_ab*>(sChi + row * KDIM + slot * 8);
        frag_ab cl = *reinterpret_cast<const frag_ab*>(sClo + row * KDIM + slot * 8);
        #pragma unroll
        for (int mf = 0; mf < 2; ++mf) {
          acc[nf][mf] = __builtin_amdgcn_mfma_f32_16x16x32_bf16(ch, xh[ks][mf], acc[nf][mf], 0, 0, 0);
          acc[nf][mf] = __builtin_amdgcn_mfma_f32_16x16x32_bf16(ch, xl[ks][mf], acc[nf][mf], 0, 0, 0);
          acc[nf][mf] = __builtin_amdgcn_mfma_f32_16x16x32_bf16(cl, xh[ks][mf], acc[nf][mf], 0, 0, 0);
        }
      }
    }

    // ---- epilogue: out = exp(-g*max(xsq+csq-2*cross,0)), float4 along n ----
    #pragma unroll
    for (int nf = 0; nf < 4; ++nf) {
      const float4 cs = *reinterpret_cast<const float4*>(sCsq + n0l + nf * 16 + g * 4);
      #pragma unroll
      for (int mf = 0; mf < 2; ++mf) {
        const f32x4 a = acc[nf][mf];
        float4 o;
        o.x = __expf(-GAMMA * fmaxf(ss[mf] + cs.x - 2.0f * a[0], 0.0f));
        o.y = __expf(-GAMMA * fmaxf(ss[mf] + cs.y - 2.0f * a[1], 0.0f));
        o.z = __expf(-GAMMA * fmaxf(ss[mf] + cs.z - 2.0f * a[2], 0.0f));
        o.w = __expf(-GAMMA * fmaxf(ss[mf] + cs.w - 2.0f * a[3], 0.0f));
        *reinterpret_cast<float4*>(
            out + ((size_t)m0 + wm * 32 + mf * 16 + r16) * (size_t)NTOT + n0g + nf * 16 + g * 4) = o;
      }
    }
  }
}

extern "C" void kernel_launch(void* const* d_in, const int* in_sizes, int n_in,
                              void* d_out, int out_size, void* d_ws, size_t ws_size,
                              hipStream_t stream) {
  (void)in_sizes; (void)n_in; (void)d_ws; (void)ws_size; (void)out_size;
  const float* x = (const float*)d_in[0];
  const float* centers = (const float*)d_in[1];
  float* out = (float*)d_out;
  const int grid = 8 * (MTOT / BM / TILES);   // 8 * 256 = 2048
  rbf_kernel<<<grid, 256, 0, stream>>>(x, centers, out);
}

// Round 4
// 81.103 us; speedup vs baseline: 2.0788x; 2.0788x over previous
//
#include <hip/hip_runtime.h>

#define GAMMA 0.1f

constexpr int MTOT = 65536;
constexpr int NTOT = 1024;
constexpr int KDIM = 64;
constexpr int BM = 128;
constexpr int BN = 128;

using frag_ab = __attribute__((ext_vector_type(8))) short;  // 8 bf16 (4 VGPRs)
using f32x4   = __attribute__((ext_vector_type(4))) float;  // 4 f32 acc

// f32 -> bf16 round-to-nearest-even; 'back' is the rounded value as f32.
__device__ __forceinline__ ushort bf16_rne(float x, float& back) {
  unsigned u = __float_as_uint(x);
  unsigned r = (u + 0x7FFFu + ((u >> 16) & 1u)) >> 16;
  back = __uint_as_float(r << 16);
  return (ushort)r;
}

// Stage a [128 rows x 64 cols] f32 tile into bf16 hi/lo LDS arrays (XOR-swizzled),
// and write per-row squared norms (from the exact f32 data) into sq[128].
__device__ __forceinline__ void stage_tile(const float* __restrict__ src,
                                           ushort* hi, ushort* lo, float* sq,
                                           int tid) {
  #pragma unroll
  for (int pass = 0; pass < 4; ++pass) {
    const int idx = pass * 2048 + tid * 8;   // flat element index in tile
    const int row = idx >> 6;                // /64
    const int s   = tid & 7;                 // 16B slot within the 128B row
    const float4* p = reinterpret_cast<const float4*>(src + idx);
    float4 v0 = p[0];
    float4 v1 = p[1];
    float v[8] = {v0.x, v0.y, v0.z, v0.w, v1.x, v1.y, v1.z, v1.w};
    frag_ab hv, lv;
    float ss = 0.0f;
    #pragma unroll
    for (int i = 0; i < 8; ++i) {
      float back;
      ushort hb = bf16_rne(v[i], back);
      float b2;
      ushort lb = bf16_rne(v[i] - back, b2);
      (void)b2;
      ss += v[i] * v[i];
      hv[i] = (short)hb;
      lv[i] = (short)lb;
    }
    ss += __shfl_xor(ss, 1);
    ss += __shfl_xor(ss, 2);
    ss += __shfl_xor(ss, 4);
    if (s == 0) sq[row] = ss;
    const int slot = s ^ (row & 7);  // bank-conflict XOR swizzle (G4)
    *reinterpret_cast<frag_ab*>(hi + row * 64 + slot * 8) = hv;
    *reinterpret_cast<frag_ab*>(lo + row * 64 + slot * 8) = lv;
  }
}

__global__ __launch_bounds__(256, 2)
void rbf_mfma_kernel(const float* __restrict__ x,
                     const float* __restrict__ centers,
                     float* __restrict__ out) {
  // 64 KB staging region, reused as the f32 out-tile for the store phase.
  __shared__ ushort sStage[4 * 8192];          // 64 KB
  ushort* sAhi = sStage;                       // 128 x 64 bf16-hi (x)
  ushort* sAlo = sStage + 8192;
  ushort* sBhi = sStage + 16384;               // 128 x 64 bf16-hi (centers)
  ushort* sBlo = sStage + 24576;
  float*  sOut = reinterpret_cast<float*>(sStage);  // union: 128 x 128 f32
  __shared__ float sAsq[BM];
  __shared__ float sBsq[BN];

  const int tid = threadIdx.x;
  const int mt = blockIdx.x >> 3;   // 512 m-tiles
  const int nt = blockIdx.x & 7;    // 8 n-tiles (adjacent blocks share the x-tile)

  stage_tile(x       + (size_t)mt * BM * KDIM, sAhi, sAlo, sAsq, tid);
  stage_tile(centers + (size_t)nt * BN * KDIM, sBhi, sBlo, sBsq, tid);
  __syncthreads();

  const int lane = tid & 63;
  const int wave = tid >> 6;
  const int wr = wave >> 1;        // wave row 0..1   (64 x-rows each)
  const int wc = wave & 1;         // wave col 0..1   (64 centers each)
  const int r16 = lane & 15;
  const int g   = lane >> 4;       // 0..3 k-group

  f32x4 acc[4][4] = {};

  #pragma unroll
  for (int ks = 0; ks < 2; ++ks) {
    const int slot = (ks * 4 + g) ^ (r16 & 7);   // matches staging swizzle
    frag_ab ah[4], al[4], bh[4], bl[4];
    #pragma unroll
    for (int m = 0; m < 4; ++m) {
      const int row = wr * 64 + m * 16 + r16;
      ah[m] = *reinterpret_cast<const frag_ab*>(sAhi + row * 64 + slot * 8);
      al[m] = *reinterpret_cast<const frag_ab*>(sAlo + row * 64 + slot * 8);
    }
    #pragma unroll
    for (int n = 0; n < 4; ++n) {
      const int row = wc * 64 + n * 16 + r16;
      bh[n] = *reinterpret_cast<const frag_ab*>(sBhi + row * 64 + slot * 8);
      bl[n] = *reinterpret_cast<const frag_ab*>(sBlo + row * 64 + slot * 8);
    }
    #pragma unroll
    for (int m = 0; m < 4; ++m) {
      #pragma unroll
      for (int n = 0; n < 4; ++n) {
        // cross = xh*ch + xh*cl + xl*ch  (lo*lo dropped, ~1e-6 rel)
        acc[m][n] = __builtin_amdgcn_mfma_f32_16x16x32_bf16(ah[m], bh[n], acc[m][n], 0, 0, 0);
        acc[m][n] = __builtin_amdgcn_mfma_f32_16x16x32_bf16(ah[m], bl[n], acc[m][n], 0, 0, 0);
        acc[m][n] = __builtin_amdgcn_mfma_f32_16x16x32_bf16(al[m], bh[n], acc[m][n], 0, 0, 0);
      }
    }
  }

  // Norms into registers BEFORE the staging LDS is overwritten.
  // xsq: rows g*4+r are consecutive -> float4 broadcast reads (conflict-free).
  float4 xs4[4];
  #pragma unroll
  for (int m = 0; m < 4; ++m)
    xs4[m] = *reinterpret_cast<const float4*>(&sAsq[wr * 64 + m * 16 + g * 4]);
  float csq_[4];
  #pragma unroll
  for (int n = 0; n < 4; ++n) csq_[n] = sBsq[wc * 64 + n * 16 + r16];

  __syncthreads();   // all frag reads done -> safe to overwrite staging with out-tile

  // ---- epilogue: exp(-g*max(xsq+csq-2*cross,0)) -> LDS out-tile (swizzled) ----
  // sOut[row][col] lives at row*128 + (cc ^ ((row>>2)&7)<<2)*4 + (col&3),
  // cc = col>>2. Write conflicts: bank = r16 + 16*((n^g)&1) -> 2-way (free).
  #pragma unroll
  for (int m = 0; m < 4; ++m) {
    #pragma unroll
    for (int r = 0; r < 4; ++r) {
      const int row = wr * 64 + m * 16 + g * 4 + r;
      const float xs = ((const float*)&xs4[m])[r];
      const int swz = ((row >> 2) & 7) << 2;
      float* orow = sOut + row * 128;
      #pragma unroll
      for (int n = 0; n < 4; ++n) {
        const int col = wc * 64 + n * 16 + r16;
        const float l2 = fmaxf(xs + csq_[n] - 2.0f * acc[m][n][r], 0.0f);
        const int cc = (col >> 2) ^ swz;
        orow[cc * 4 + (col & 3)] = __expf(-GAMMA * l2);
      }
    }
  }
  __syncthreads();

  // ---- streamed store: each inst = 2 rows x 512B contiguous (full 128B lines) ----
  const size_t row0 = (size_t)mt * BM;
  const int col0 = nt * BN;
  #pragma unroll
  for (int p = 0; p < 16; ++p) {
    const int q = p * 256 + tid;        // 16B chunk id: 128 rows x 32 chunks
    const int row = q >> 5;
    const int cc = q & 31;
    const int ccs = cc ^ (((row >> 2) & 7) << 2);
    const f32x4 v = *reinterpret_cast<const f32x4*>(sOut + row * 128 + ccs * 4);
    *reinterpret_cast<f32x4*>(out + (row0 + row) * (size_t)NTOT + col0 + cc * 4) = v;
  }
}

extern "C" void kernel_launch(void* const* d_in, const int* in_sizes, int n_in,
                              void* d_out, int out_size, void* d_ws, size_t ws_size,
                              hipStream_t stream) {
  (void)in_sizes; (void)n_in; (void)d_ws; (void)ws_size; (void)out_size;
  const float* x       = (const float*)d_in[0];
  const float* centers = (const float*)d_in[1];
  float* out = (float*)d_out;
  const int grid = (MTOT / BM) * (NTOT / BN);   // 512 * 8 = 4096
  rbf_mfma_kernel<<<grid, 256, 0, stream>>>(x, centers, out);
}